// Round 1
// baseline (435.701 us; speedup 1.0000x reference)
//
#include <hip/hip_runtime.h>

// LM-LIIF fused pipeline, fp32.
//   feat:(1,64,96,96) coord/cell:(1,147456,2)
//   hyper: hyp_in(578) -> relu(@Wh1+bh1)(256) -> @Wh2+bh2 (256)  per latent px
//   query: 4-tap ensemble, modulated 2-hidden MLP 68->64->64->3
//
// Kernel 1 (hyper_kernel): per 16-px row strip, stages 3x18x64 feat patch in
//   LDS, computes F0 = feat@W0[0:64]+b0 (layer-0 precompute), conv3x3-style
//   layer1 (576->256), LDS transpose, layer2 (256->256). Writes mod_ws, f0_ws.
// Kernel 2 (query_kernel): thread = query, 4 ensembles unrolled. Layer0
//   collapses to F0 gather + 4 rank-1 terms; layer1 via rolled K-loop with
//   per-lane x from LDS and wave-uniform W1 rows (scalar loads).

#define HW 96
#define NPIX (96*96)
#define CFEAT 64
#define QTOT 147456

__global__ __launch_bounds__(256) void hyper_kernel(
    const float* __restrict__ feat,
    const float* __restrict__ cell,
    const float* __restrict__ Wh1,   // (578,256)
    const float* __restrict__ bh1,   // (256)
    const float* __restrict__ Wh2,   // (256,256)
    const float* __restrict__ bh2,   // (256)
    const float* __restrict__ W0,    // (68,64)
    const float* __restrict__ b0,    // (64)
    float* __restrict__ mod_ws,      // (9216,256)
    float* __restrict__ f0_ws)       // (9216,64)
{
    __shared__ float patch[CFEAT*54];   // [c][dy(3)][xx(18)]  13.8 KB
    __shared__ float h1s[256*17];       // [n][m pad 17]       17.4 KB

    const int tid = threadIdx.x;
    const int blk = blockIdx.x;
    const int y   = blk / 6;
    const int x0  = (blk % 6) * 16;

    // stage 3x18 patch of all 64 channels (zero-padded at borders)
    for (int idx = tid; idx < CFEAT*54; idx += 256) {
        int c  = idx / 54;
        int r  = idx % 54;
        int dy = r / 18;
        int xx = r % 18;
        int gy = y + dy - 1;
        int gx = x0 + xx - 1;
        float v = 0.0f;
        if (gy >= 0 && gy < HW && gx >= 0 && gx < HW)
            v = feat[c*NPIX + gy*HW + gx];
        patch[idx] = v;
    }
    __syncthreads();

    const int lane  = tid & 63;   // channel (quad) id
    const int mg    = tid >> 6;   // pixel group 0..3
    const int m0    = mg * 4;
    const int qbase = y*HW + x0;

    // ---- F0[p][n] = sum_c feat[c,p]*W0[c,n] + b0[n]  (layer-0 precompute) ----
    {
        float acc[4] = {0.f, 0.f, 0.f, 0.f};
        for (int c = 0; c < CFEAT; ++c) {
            float w = W0[c*64 + lane];
            const float* p = &patch[c*54 + 18 + 1 + m0];   // center tap
            acc[0] = fmaf(p[0], w, acc[0]);
            acc[1] = fmaf(p[1], w, acc[1]);
            acc[2] = fmaf(p[2], w, acc[2]);
            acc[3] = fmaf(p[3], w, acc[3]);
        }
        float bb = b0[lane];
        #pragma unroll
        for (int mi = 0; mi < 4; ++mi)
            f0_ws[(qbase + m0 + mi)*64 + lane] = acc[mi] + bb;
    }

    // ---- hyper layer 1: 576-unfold -> 256, thread owns 4 px x 4 ch ----
    float acc[4][4];
    #pragma unroll
    for (int i = 0; i < 4; ++i) {
        acc[i][0] = 0.f; acc[i][1] = 0.f; acc[i][2] = 0.f; acc[i][3] = 0.f;
    }

    const float4* Wh1v = (const float4*)Wh1;
    for (int c = 0; c < CFEAT; ++c) {
        #pragma unroll
        for (int dy = 0; dy < 3; ++dy) {
            #pragma unroll
            for (int dx = 0; dx < 3; ++dx) {
                const int k = c*9 + dy*3 + dx;
                const float4 w = Wh1v[k*64 + lane];
                const float* p = &patch[c*54 + dy*18 + dx + m0];
                #pragma unroll
                for (int mi = 0; mi < 4; ++mi) {
                    float xv = p[mi];
                    acc[mi][0] = fmaf(xv, w.x, acc[mi][0]);
                    acc[mi][1] = fmaf(xv, w.y, acc[mi][1]);
                    acc[mi][2] = fmaf(xv, w.z, acc[mi][2]);
                    acc[mi][3] = fmaf(xv, w.w, acc[mi][3]);
                }
            }
        }
    }

    // epilogue: + rel_cell rows (576,577) + bias, relu, transpose into LDS
    {
        const float4 bb   = ((const float4*)bh1)[lane];
        const float4 w576 = Wh1v[576*64 + lane];
        const float4 w577 = Wh1v[577*64 + lane];
        #pragma unroll
        for (int mi = 0; mi < 4; ++mi) {
            const int q = qbase + m0 + mi;
            const float rc0 = cell[q*2+0] * 96.0f;
            const float rc1 = cell[q*2+1] * 96.0f;
            float v0 = acc[mi][0] + bb.x + rc0*w576.x + rc1*w577.x;
            float v1 = acc[mi][1] + bb.y + rc0*w576.y + rc1*w577.y;
            float v2 = acc[mi][2] + bb.z + rc0*w576.z + rc1*w577.z;
            float v3 = acc[mi][3] + bb.w + rc0*w576.w + rc1*w577.w;
            h1s[(4*lane+0)*17 + m0 + mi] = fmaxf(v0, 0.f);
            h1s[(4*lane+1)*17 + m0 + mi] = fmaxf(v1, 0.f);
            h1s[(4*lane+2)*17 + m0 + mi] = fmaxf(v2, 0.f);
            h1s[(4*lane+3)*17 + m0 + mi] = fmaxf(v3, 0.f);
        }
    }
    __syncthreads();

    // ---- hyper layer 2: 256 -> 256 ----
    float acc2[4][4];
    #pragma unroll
    for (int i = 0; i < 4; ++i) {
        acc2[i][0] = 0.f; acc2[i][1] = 0.f; acc2[i][2] = 0.f; acc2[i][3] = 0.f;
    }
    const float4* Wh2v = (const float4*)Wh2;
    for (int k = 0; k < 256; ++k) {
        const float4 w = Wh2v[k*64 + lane];
        const float* p = &h1s[k*17 + m0];
        #pragma unroll
        for (int mi = 0; mi < 4; ++mi) {
            float xv = p[mi];
            acc2[mi][0] = fmaf(xv, w.x, acc2[mi][0]);
            acc2[mi][1] = fmaf(xv, w.y, acc2[mi][1]);
            acc2[mi][2] = fmaf(xv, w.z, acc2[mi][2]);
            acc2[mi][3] = fmaf(xv, w.w, acc2[mi][3]);
        }
    }
    {
        const float4 bb = ((const float4*)bh2)[lane];
        #pragma unroll
        for (int mi = 0; mi < 4; ++mi) {
            const int q = qbase + m0 + mi;
            float4 o;
            o.x = acc2[mi][0] + bb.x;
            o.y = acc2[mi][1] + bb.y;
            o.z = acc2[mi][2] + bb.z;
            o.w = acc2[mi][3] + bb.w;
            ((float4*)mod_ws)[q*64 + lane] = o;
        }
    }
}

__global__ __launch_bounds__(64, 3) void query_kernel(
    const float* __restrict__ coord,
    const float* __restrict__ cell,
    const float* __restrict__ W0,      // rows 64..67 used here
    const float* __restrict__ W1,      // (64,64)
    const float* __restrict__ b1,      // (64)
    const float* __restrict__ W2,      // (64,3)
    const float* __restrict__ b2,      // (3)
    const float* __restrict__ mod_ws,  // (9216,256)
    const float* __restrict__ f0_ws,   // (9216,64)
    float* __restrict__ out)           // (Q,3)
{
    __shared__ float hbuf[64*64];      // [k][m]  16 KB -> 10 blocks/CU

    const int tid = threadIdx.x;
    const int q   = blockIdx.x * 64 + tid;

    const float cy  = coord[q*2 + 0];
    const float cx  = coord[q*2 + 1];
    const float rc0 = cell[q*2 + 0] * 96.0f;
    const float rc1 = cell[q*2 + 1] * 96.0f;

    // per-ensemble gather index + rel + area (e: vx outer {-1,1}, vy inner)
    int   rmA[4];
    float r0A[4], r1A[4], areaA[4];
    #pragma unroll
    for (int e = 0; e < 4; ++e) {
        const float vx = (e < 2) ? -1.0f : 1.0f;
        const float vy = (e & 1) ? 1.0f : -1.0f;
        float ey = cy + vx*(1.0f/96.0f) + 1e-6f;
        float ex = cx + vy*(1.0f/96.0f) + 1e-6f;
        ey = fminf(fmaxf(ey, -1.0f + 1e-6f), 1.0f - 1e-6f);
        ex = fminf(fmaxf(ex, -1.0f + 1e-6f), 1.0f - 1e-6f);
        int iy = (int)rintf((ey + 1.0f) * 48.0f - 0.5f);
        int ix = (int)rintf((ex + 1.0f) * 48.0f - 0.5f);
        iy = min(max(iy, 0), 95);
        ix = min(max(ix, 0), 95);
        const float qy = ((iy + 0.5f) / 96.0f) * 2.0f - 1.0f;
        const float qx = ((ix + 0.5f) / 96.0f) * 2.0f - 1.0f;
        const float r0 = (cy - qy) * 96.0f;
        const float r1 = (cx - qx) * 96.0f;
        rmA[e]   = iy*96 + ix;
        r0A[e]   = r0;
        r1A[e]   = r1;
        areaA[e] = fabsf(r0 * r1) + 1e-9f;
    }
    const float tot = areaA[0] + areaA[1] + areaA[2] + areaA[3];

    float oa0 = 0.f, oa1 = 0.f, oa2 = 0.f;

    #pragma unroll
    for (int e = 0; e < 4; ++e) {
        const int   rm = rmA[e];
        const float r0 = r0A[e];
        const float r1 = r1A[e];
        const float4* F0v  = (const float4*)(f0_ws + (size_t)rm*64);
        const float4* modv = (const float4*)(mod_ws + (size_t)rm*256);
        const float4* w64v = (const float4*)(W0 + 64*64);
        const float4* w65v = (const float4*)(W0 + 65*64);
        const float4* w66v = (const float4*)(W0 + 66*64);
        const float4* w67v = (const float4*)(W0 + 67*64);

        // layer 0 (collapsed): h = F0 + r0*W0[64] + r1*W0[65] + rc*W0[66,67]
        // then modulate (scale mod[0:64], shift mod[128:192]) + relu
        float h[64];
        #pragma unroll
        for (int n4 = 0; n4 < 16; ++n4) {
            const float4 f  = F0v[n4];
            const float4 a  = w64v[n4];
            const float4 b  = w65v[n4];
            const float4 c  = w66v[n4];
            const float4 d  = w67v[n4];
            const float4 sc = modv[n4];
            const float4 sh = modv[32 + n4];
            float hx = f.x + r0*a.x + r1*b.x + rc0*c.x + rc1*d.x;
            float hy = f.y + r0*a.y + r1*b.y + rc0*c.y + rc1*d.y;
            float hz = f.z + r0*a.z + r1*b.z + rc0*c.z + rc1*d.z;
            float hw = f.w + r0*a.w + r1*b.w + rc0*c.w + rc1*d.w;
            h[n4*4+0] = fmaxf(fmaf(hx, sc.x, sh.x), 0.f);
            h[n4*4+1] = fmaxf(fmaf(hy, sc.y, sh.y), 0.f);
            h[n4*4+2] = fmaxf(fmaf(hz, sc.z, sh.z), 0.f);
            h[n4*4+3] = fmaxf(fmaf(hw, sc.w, sh.w), 0.f);
        }

        __syncthreads();                     // prior reads of hbuf done
        #pragma unroll
        for (int n = 0; n < 64; ++n)
            hbuf[n*64 + tid] = h[n];
        __syncthreads();

        // layer 1: rolled K-loop; W1 row is wave-uniform (scalar loads),
        // x_k per-lane from LDS -> static h2[] indexing only
        float h2[64];
        #pragma unroll
        for (int n = 0; n < 64; ++n) h2[n] = b1[n];
        for (int k = 0; k < 64; ++k) {
            const float xk = hbuf[k*64 + tid];
            const float* wr = W1 + k*64;
            #pragma unroll
            for (int n = 0; n < 64; ++n)
                h2[n] = fmaf(xk, wr[n], h2[n]);
        }

        // modulate2 (scale mod[64:128], shift mod[192:256]) + relu, layer 2
        float o0 = b2[0], o1 = b2[1], o2 = b2[2];
        #pragma unroll
        for (int n4 = 0; n4 < 16; ++n4) {
            const float4 sc = modv[16 + n4];
            const float4 sh = modv[48 + n4];
            float v0 = fmaxf(fmaf(h2[n4*4+0], sc.x, sh.x), 0.f);
            float v1 = fmaxf(fmaf(h2[n4*4+1], sc.y, sh.y), 0.f);
            float v2 = fmaxf(fmaf(h2[n4*4+2], sc.z, sh.z), 0.f);
            float v3 = fmaxf(fmaf(h2[n4*4+3], sc.w, sh.w), 0.f);
            const int n0 = n4*4;
            o0 = fmaf(v0, W2[(n0+0)*3+0], o0);
            o1 = fmaf(v0, W2[(n0+0)*3+1], o1);
            o2 = fmaf(v0, W2[(n0+0)*3+2], o2);
            o0 = fmaf(v1, W2[(n0+1)*3+0], o0);
            o1 = fmaf(v1, W2[(n0+1)*3+1], o1);
            o2 = fmaf(v1, W2[(n0+1)*3+2], o2);
            o0 = fmaf(v2, W2[(n0+2)*3+0], o0);
            o1 = fmaf(v2, W2[(n0+2)*3+1], o1);
            o2 = fmaf(v2, W2[(n0+2)*3+2], o2);
            o0 = fmaf(v3, W2[(n0+3)*3+0], o0);
            o1 = fmaf(v3, W2[(n0+3)*3+1], o1);
            o2 = fmaf(v3, W2[(n0+3)*3+2], o2);
        }

        // diagonal-swapped area weight
        const float wgt = areaA[3 - e];
        oa0 = fmaf(o0, wgt, oa0);
        oa1 = fmaf(o1, wgt, oa1);
        oa2 = fmaf(o2, wgt, oa2);
    }

    const float inv = 1.0f / tot;
    out[q*3 + 0] = oa0 * inv;
    out[q*3 + 1] = oa1 * inv;
    out[q*3 + 2] = oa2 * inv;
}

extern "C" void kernel_launch(void* const* d_in, const int* in_sizes, int n_in,
                              void* d_out, int out_size, void* d_ws, size_t ws_size,
                              hipStream_t stream) {
    const float* feat  = (const float*)d_in[0];
    const float* coord = (const float*)d_in[1];
    const float* cell  = (const float*)d_in[2];
    const float* Wh1   = (const float*)d_in[3];
    const float* bh1   = (const float*)d_in[4];
    const float* Wh2   = (const float*)d_in[5];
    const float* bh2   = (const float*)d_in[6];
    const float* W0    = (const float*)d_in[7];
    const float* b0    = (const float*)d_in[8];
    const float* W1    = (const float*)d_in[9];
    const float* b1    = (const float*)d_in[10];
    const float* W2    = (const float*)d_in[11];
    const float* b2    = (const float*)d_in[12];
    float* out = (float*)d_out;

    float* mod_ws = (float*)d_ws;                    // 9216*256 f32 = 9.44 MB
    float* f0_ws  = (float*)d_ws + 9216*256;         // 9216*64  f32 = 2.36 MB

    hyper_kernel<<<dim3(576), dim3(256), 0, stream>>>(
        feat, cell, Wh1, bh1, Wh2, bh2, W0, b0, mod_ws, f0_ws);
    query_kernel<<<dim3(2304), dim3(64), 0, stream>>>(
        coord, cell, W0, W1, b1, W2, b2, mod_ws, f0_ws, out);
}